// Round 2
// baseline (352.086 us; speedup 1.0000x reference)
//
#include <hip/hip_runtime.h>

#define INPUT 32
#define HIDDEN 64
#define BATCH 4096
#define SEQ 256

typedef __attribute__((ext_vector_type(8))) short bf16x8;   // 8 bf16 (4 VGPRs)
typedef __attribute__((ext_vector_type(4))) float floatx4;  // 4 fp32

#define MFMA(a, b, c) __builtin_amdgcn_mfma_f32_16x16x32_bf16((a), (b), (c), 0, 0, 0)

// LDS-only barrier: wait LDS ops, leave global (DMA) loads in flight.
#define LDS_BARRIER() asm volatile("s_waitcnt lgkmcnt(0)\n\ts_barrier" ::: "memory")

// Async global->LDS DMA, 16B per lane, LDS dest = uniform base + lane*16.
__device__ __forceinline__ void load_lds16(const float* g, void* l) {
    __builtin_amdgcn_global_load_lds(
        (const __attribute__((address_space(1))) void*)g,
        (__attribute__((address_space(3))) void*)l, 16, 0, 0);
}

// RNE f32->bf16 scalar (setup-only).
__device__ __forceinline__ unsigned short f2bf(float f) {
    unsigned u = __float_as_uint(f);
    u += 0x7fffu + ((u >> 16) & 1u);
    return (unsigned short)(u >> 16);
}
__device__ __forceinline__ float bf2f(unsigned short b) {
    return __uint_as_float(((unsigned)b) << 16);
}
__device__ __forceinline__ void split8(const float f[8], bf16x8& hi, bf16x8& lo) {
#pragma unroll
    for (int j = 0; j < 8; ++j) {
        unsigned short h = f2bf(f[j]);
        hi[j] = (short)h;
        lo[j] = (short)f2bf(f[j] - bf2f(h));
    }
}

// Truncation split of a pair -> packed hi/lo words (6 VALU). Used for x.
__device__ __forceinline__ void packpair(float f0, float f1, unsigned& hw, unsigned& lw) {
    unsigned b0 = __float_as_uint(f0), b1 = __float_as_uint(f1);
    float h0 = __uint_as_float(b0 & 0xffff0000u);
    float h1 = __uint_as_float(b1 & 0xffff0000u);
    float l0 = f0 - h0, l1 = f1 - h1;
    hw = __builtin_amdgcn_perm(b1, b0, 0x07060302u);
    lw = __builtin_amdgcn_perm(__float_as_uint(l1), __float_as_uint(l0), 0x07060302u);
}

// RNE pack of a pair (recurrent state: accuracy matters).
__device__ __forceinline__ unsigned pack_rne(float f0, float f1) {
    unsigned r0 = __float_as_uint(f0);
    r0 += 0x7fffu + ((r0 >> 16) & 1u);
    unsigned r1 = __float_as_uint(f1);
    r1 += 0x7fffu + ((r1 >> 16) & 1u);
    return __builtin_amdgcn_perm(r1, r0, 0x07060302u);
}

union FragU { bf16x8 v; unsigned u[4]; };

__device__ __forceinline__ void pack8(float4 a, float4 b, FragU& H, FragU& L) {
    packpair(a.x, a.y, H.u[0], L.u[0]);
    packpair(a.z, a.w, H.u[1], L.u[1]);
    packpair(b.x, b.y, H.u[2], L.u[2]);
    packpair(b.z, b.w, H.u[3], L.u[3]);
}

// Round-14: r13's asm-register prefetch NaN'd (compiler copies of in-flight
// load destinations). Same diagnosis (r12's register x-prefetch collapsed by
// the scheduler -> exposed HBM/L2 latency each step), safe mechanism:
// x tiles prefetched via global_load_lds DMA into a 4-slot LDS ring — no
// VGPR destination exists, so no copy/sink/remat hazard is possible.
//   tile u: DMA-issued at step u-4 by wave u&3; issuer drains vmcnt(0)
//   before the barrier ending step u-2 (>=2 full steps to land); read by all
//   waves at step u-1 (2x ds_read_b128, lane-linear, conflict-free), packed
//   locally (r12 math), consumed as ihn; feeds the hh chain at step u.
// Prologue: ih_0 from plain loads; waves 1..3 DMA tiles 1..3; __syncthreads
// (drains vmcnt) publishes them. Numerics BIT-IDENTICAL to the verified
// 287us kernel (same packpair/pack_rne, same MFMA order: depth-2 hi chain +
// parallel depth-2 lo chain, same G swizzle) -> absmax must reproduce.
// Layouts (verified r5-r11): C/D row(m)=4qd+r, col(n)=ln. A: m=ln, k=8qd+j.
//   B: n=ln, k=8qd+j (+32kt). A=W rows (u=16nt+ln), B=state G[k=u][n=batch].
// G in LDS (u16): buf*1024 + kt*512 + ln*32 + slot*8 + j, slot=(qd+(ln>>1))&3.
// X ring (f32): slot*512 + lane*4 (+256 for the second 16B half).
__global__ __launch_bounds__(256, 1) void rnn_ns4_kernel(
    const float* __restrict__ x,     // [B, T, 32]
    const float* __restrict__ W_ih,  // [64, 32]
    const float* __restrict__ W_hh,  // [64, 64]
    const float* __restrict__ b_ih,  // [64]
    const float* __restrict__ b_hh,  // [64]
    const float* __restrict__ W_fc,  // [1, 64]
    const float* __restrict__ b_fc,  // [1]
    float* __restrict__ out)         // [B, 1]
{
    const int tid  = threadIdx.x;
    const int nt   = tid >> 6;        // wave id: owns hidden rows [16nt, 16nt+16)
    const int lane = tid & 63;
    const int ln   = lane & 15;
    const int qd   = lane >> 4;
    const int b0   = blockIdx.x * 16;

    __shared__ __align__(16) unsigned short Gs[2048];  // 4 KB: 2 bufs, h hi plane
    __shared__ __align__(16) float Xs[2048];           // 8 KB: 4-slot raw-x ring
    __shared__ float Ps[64];

    { // zero buffer 0 (h_{-1} = 0)
        unsigned* z = (unsigned*)Gs;
        for (int i = tid; i < 512; i += 256) z[i] = 0u;
    }

    // ---- Static A-operand weights for THIS wave's u-tile ----
    const int mrow = nt * 16 + ln;
    bf16x8 WihH, WihL, WhhH[2], WhhL[2];
    {
        float f[8];
        const float* ri = W_ih + mrow * INPUT + qd * 8;
        *(float4*)&f[0] = *(const float4*)ri;
        *(float4*)&f[4] = *(const float4*)(ri + 4);
        split8(f, WihH, WihL);
        const float* rh = W_hh + mrow * HIDDEN + qd * 8;
#pragma unroll
        for (int kt = 0; kt < 2; ++kt) {
            *(float4*)&f[0] = *(const float4*)(rh + kt * 32);
            *(float4*)&f[4] = *(const float4*)(rh + kt * 32 + 4);
            split8(f, WhhH[kt], WhhL[kt]);
        }
    }
    const int u0 = nt * 16 + qd * 4;   // this lane's 4 output rows
    floatx4 bbv, wfcv;
    {
        float4 bi = *(const float4*)(b_ih + u0);
        float4 bh = *(const float4*)(b_hh + u0);
        bbv[0] = bi.x + bh.x; bbv[1] = bi.y + bh.y;
        bbv[2] = bi.z + bh.z; bbv[3] = bi.w + bh.w;
        float4 wf = *(const float4*)(W_fc + u0);
        wfcv[0] = wf.x; wfcv[1] = wf.y; wfcv[2] = wf.z; wfcv[3] = wf.w;
    }

    // Reader base (B-frag) and writer base (this lane's 4 contiguous u).
    const int rbase = ln * 32 + ((qd + (ln >> 1)) & 3) * 8;
    const int wbase = (u0 >> 5) * 512 + ln * 32 +
                      ((((u0 >> 3) & 3) + (ln >> 1)) & 3) * 8 + (u0 & 7);

    const float* xp = x + (size_t)(b0 + ln) * (SEQ * INPUT) + qd * 8;

    // ---- Prologue ----
    // ih-projection for t=0 from plain loads (compiler-managed waits).
    floatx4 ihacc;
    {
        float4 x0a = *(const float4*)(xp);
        float4 x0b = *(const float4*)(xp + 4);
        FragU xH, xL;
        pack8(x0a, x0b, xH, xL);
        ihacc = MFMA(WihH, xH.v, bbv);
        ihacc = MFMA(WihH, xL.v, ihacc);
        ihacc = MFMA(WihL, xH.v, ihacc);
    }
    // Prime ring slots 1..3 with tiles 1..3 (wave w -> tile w).
    if (nt > 0) {
        load_lds16(xp + nt * INPUT,     &Xs[nt * 512]);
        load_lds16(xp + nt * INPUT + 4, &Xs[nt * 512 + 256]);
    }

    __syncthreads();   // zero-init + primed tiles visible (drains vmcnt too)

    float hv[4];

#pragma unroll 1
    for (int tb = 0; tb < SEQ; tb += 4) {
#pragma unroll
        for (int s = 0; s < 4; ++s) {
            const int t = tb + s;

            // Critical: read h_{t-1} frags (written last step / zero-init).
            const unsigned short* Hr = Gs + ((t & 1) << 10) + rbase;
            bf16x8 g0 = *(const bf16x8*)(Hr);
            bf16x8 g1 = *(const bf16x8*)(Hr + 512);

            // Off-path: raw x_{t+1} from the ring (landed >=1 step ago),
            // pack (r12 math), ihn = ih_{t+1}.
            const float* Xr = Xs + (((t + 1) & 3) << 9) + (lane << 2);
            float4 ra = *(const float4*)(Xr);
            float4 rb = *(const float4*)(Xr + 256);
            FragU nxH, nxL;
            pack8(ra, rb, nxH, nxL);
            floatx4 ihn = MFMA(WihH, nxH.v, bbv);
            ihn = MFMA(WihH, nxL.v, ihn);
            ihn = MFMA(WihL, nxH.v, ihn);

            // DMA-issue tile t+4 into slot s (previous tenant read at t-1).
            if (nt == s) {
                const int tn = (t + 4 < SEQ) ? t + 4 : SEQ - 1;
                load_lds16(xp + tn * INPUT,     &Xs[s * 512]);
                load_lds16(xp + tn * INPUT + 4, &Xs[s * 512 + 256]);
            }

            // hh critical path: depth-2 main + parallel depth-2 lo-correction
            // (bit-identical to r12).
            floatx4 a = MFMA(WhhH[0], g0, ihacc);
            a = MFMA(WhhH[1], g1, a);
            floatx4 c = {0.f, 0.f, 0.f, 0.f};
            c = MFMA(WhhL[0], g0, c);
            c = MFMA(WhhL[1], g1, c);

            // tanh of this wave's 4 elements.
#pragma unroll
            for (int r = 0; r < 4; ++r) {
                float p = a[r] + c[r];
                float e = __expf(2.0f * p);
                hv[r] = 1.0f - 2.0f * __builtin_amdgcn_rcpf(e + 1.0f);
            }

            // Pack 4 -> 2 u32, ONE ds_write_b64 into the other buffer.
            unsigned w0 = pack_rne(hv[0], hv[1]);
            unsigned w1 = pack_rne(hv[2], hv[3]);
            uint2 wv; wv.x = w0; wv.y = w1;
            *(uint2*)(Gs + (((t & 1) ^ 1) << 10) + wbase) = wv;

            ihacc = ihn;

            // The wave that DMA-issued at step t-2 drains its own loads
            // (>=2 full steps in flight -> ~free) before the publishing
            // barrier; slot s becomes readable at step t+3... i.e. tile t+4
            // at step t+3 after the chain of barriers.
            if (nt == ((s + 2) & 3))
                asm volatile("s_waitcnt vmcnt(0)" ::: "memory");

            LDS_BARRIER();   // LDS-only drain; newer DMA loads stay in flight.
        }
    }

    // Drain this wave's leftover (clamped-tile) DMA loads.
    asm volatile("s_waitcnt vmcnt(0)" ::: "memory");

    // ---- Head: out[b] = sum_u wfc[u] * h[u][b] + b_fc ----
    float acc = wfcv[0] * hv[0] + wfcv[1] * hv[1] + wfcv[2] * hv[2] + wfcv[3] * hv[3];
    acc += __shfl_xor(acc, 16, 64);
    acc += __shfl_xor(acc, 32, 64);
    if (qd == 0) Ps[nt * 16 + ln] = acc;
    __syncthreads();
    if (tid < 16)
        out[b0 + tid] = Ps[tid] + Ps[16 + tid] + Ps[32 + tid] + Ps[48 + tid] + b_fc[0];
}

extern "C" void kernel_launch(void* const* d_in, const int* in_sizes, int n_in,
                              void* d_out, int out_size, void* d_ws, size_t ws_size,
                              hipStream_t stream) {
    const float* x    = (const float*)d_in[0];
    const float* W_ih = (const float*)d_in[1];
    const float* W_hh = (const float*)d_in[2];
    const float* b_ih = (const float*)d_in[3];
    const float* b_hh = (const float*)d_in[4];
    const float* W_fc = (const float*)d_in[5];
    const float* b_fc = (const float*)d_in[6];
    float* out = (float*)d_out;

    // 256 tiles of 16 chains; 4 waves/block (one per SIMD), 1 block per CU.
    rnn_ns4_kernel<<<dim3(BATCH / 16), dim3(256), 0, stream>>>(
        x, W_ih, W_hh, b_ih, b_hh, W_fc, b_fc, out);
}